// Round 6
// baseline (204.209 us; speedup 1.0000x reference)
//
#include <hip/hip_runtime.h>
#include <hip/hip_cooperative_groups.h>
#include <cmath>

namespace cg = cooperative_groups;

#define T_LEN 262144
#define NROW 8
#define C 42                      /* positions per lane (registers) */
#define EXTW (64 * C)             /* 2688-position window per wave */
#define HALO 576
#define USEFUL (EXTW - HALO)      /* 2112 */
#define WPR 125                   /* waves per row = ceil(262144/2112) */
#define NWAVE (NROW * WPR)        /* 1000 */
#define WPB 4                     /* waves per block */
#define NBLK (NWAVE / WPB)        /* 250 blocks, all co-resident */
#define LDSP (C + 1)              /* padded LDS stride per lane */

#define EIGHT_LN2 5.545177444479562f

__device__ __forceinline__ float fast_rcp(float x) { return __builtin_amdgcn_rcpf(x); }

// One gated residual layer, fully in registers. Dilation D compile-time.
// Neighbor taps (reach 4*D <= 32) come from lane-1 via shfl_up, captured
// before any h update; j descends so in-place update never clobbers a tap.
template<int D>
__device__ __forceinline__ void glayer(
    int k,
    const float* __restrict__ fw, const float* __restrict__ fb,
    const float* __restrict__ gw, const float* __restrict__ gb,
    const float* __restrict__ rwp, const float* __restrict__ rbp,
    float (&h)[C], float (&skip)[C])
{
    const float f0 = fw[k*5+0], f1 = fw[k*5+1], f2 = fw[k*5+2], f3 = fw[k*5+3], f4 = fw[k*5+4];
    const float fbk = fb[k];
    const float g0 = gw[k*5+0], g1 = gw[k*5+1], g2 = gw[k*5+2], g3 = gw[k*5+3], g4 = gw[k*5+4];
    const float gbk = gb[k];
    const float rwk = rwp[k], rbk = rbp[k];

    float nb[4*D];                 // neighbor's top 4D values (old h)
    #pragma unroll
    for (int m = 0; m < 4*D; ++m) nb[m] = __shfl_up(h[C - 4*D + m], 1);

    auto TAP = [&](int j, int kk) -> float {
        const int idx = j - kk*D;
        return (idx >= 0) ? h[idx] : nb[idx + 4*D];
    };

    #pragma unroll
    for (int jp = C - 2; jp >= 0; jp -= 2) {
        const int ja = jp + 1, jb = jp;
        const float a0 = TAP(ja,4), a1 = TAP(ja,3), a2 = TAP(ja,2), a3 = TAP(ja,1), a4 = h[ja];
        const float b0 = TAP(jb,4), b1 = TAP(jb,3), b2 = TAP(jb,2), b3 = TAP(jb,1), b4 = h[jb];

        float afa = fbk, aga = gbk, afb = fbk, agb = gbk;
        afa = fmaf(f0,a0,afa); afa = fmaf(f1,a1,afa); afa = fmaf(f2,a2,afa);
        afa = fmaf(f3,a3,afa); afa = fmaf(f4,a4,afa);
        aga = fmaf(g0,a0,aga); aga = fmaf(g1,a1,aga); aga = fmaf(g2,a2,aga);
        aga = fmaf(g3,a3,aga); aga = fmaf(g4,a4,aga);
        afb = fmaf(f0,b0,afb); afb = fmaf(f1,b1,afb); afb = fmaf(f2,b2,afb);
        afb = fmaf(f3,b3,afb); afb = fmaf(f4,b4,afb);
        agb = fmaf(g0,b0,agb); agb = fmaf(g1,b1,agb); agb = fmaf(g2,b2,agb);
        agb = fmaf(g3,b3,agb); agb = fmaf(g4,b4,agb);

        // z = tanh(af)*sigmoid(ag) = (E1-1)/((E1+1)(1+E2)); shared rcp per pair
        const float e1a = __expf(afa + afa), e2a = __expf(-aga);
        const float e1b = __expf(afb + afb), e2b = __expf(-agb);
        const float Da = (e1a + 1.0f) * (1.0f + e2a);
        const float Db = (e1b + 1.0f) * (1.0f + e2b);
        const float r  = fast_rcp(Da * Db);
        const float za = (e1a - 1.0f) * Db * r;
        const float zb = (e1b - 1.0f) * Da * r;

        skip[ja] += za; skip[jb] += zb;
        h[ja] = fmaf(za, rwk, rbk) + a4;
        h[jb] = fmaf(zb, rwk, rbk) + b4;
    }
}

// ---------------------------------------------------------------------------
__global__ __launch_bounds__(256)
void k_fused(const float* __restrict__ x,
             const float* __restrict__ cw,  const float* __restrict__ cb,
             const float* __restrict__ fw,  const float* __restrict__ fb,
             const float* __restrict__ gw,  const float* __restrict__ gb,
             const float* __restrict__ rw,  const float* __restrict__ rb,
             const float* __restrict__ c1w, const float* __restrict__ c1b,
             const float* __restrict__ c2w, const float* __restrict__ c2b,
             float* __restrict__ out, float* __restrict__ partsum)
{
    __shared__ float stg[WPB][64 * LDSP];   // 4 x 11008 B = 44 KB

    const int tid = threadIdx.x;
    const int l   = tid & 63;
    const int w   = tid >> 6;
    const int gtile = blockIdx.x * WPB + w;
    const int row   = gtile / WPR;
    const int u     = gtile % WPR;
    const long long P0 = (long long)u * USEFUL - HALO;

    float* slice = &stg[w][0];
    const float* xr = x + (size_t)row * T_LEN;

    // stage input: coalesced global -> lane-blocked LDS (padded)
    #pragma unroll 1
    for (int it = 0; it < C; ++it) {
        const int i = l + 64 * it;
        const long long g = P0 + i;
        const float v = (g >= 0 && g < T_LEN) ? xr[g] : 0.0f;
        stg[w][(i / C) * LDSP + (i % C)] = v;
    }
    __syncthreads();

    float h[C], skip[C];
    #pragma unroll
    for (int j = 0; j < C; ++j) { h[j] = slice[l * LDSP + j]; skip[j] = 0.0f; }

    // initial causal conv (d=1), in place, descending j
    {
        float nb[4];
        #pragma unroll
        for (int m = 0; m < 4; ++m) nb[m] = __shfl_up(h[C - 4 + m], 1);
        const float q0 = cw[0], q1 = cw[1], q2 = cw[2], q3 = cw[3], q4 = cw[4], qb = cb[0];
        #pragma unroll
        for (int j = C - 1; j >= 0; --j) {
            const float t0 = (j-4 >= 0) ? h[j-4] : nb[j];
            const float t1 = (j-3 >= 0) ? h[j-3] : nb[j+1];
            const float t2 = (j-2 >= 0) ? h[j-2] : nb[j+2];
            const float t3 = (j-1 >= 0) ? h[j-1] : nb[j+3];
            float acc = qb;
            acc = fmaf(q0, t0, acc); acc = fmaf(q1, t1, acc); acc = fmaf(q2, t2, acc);
            acc = fmaf(q3, t3, acc); acc = fmaf(q4, h[j], acc);
            h[j] = acc;
        }
    }

    // 30 layers: d=1, then (2,4,8,6) x 7, then d=2
    glayer<1>(0, fw, fb, gw, gb, rw, rb, h, skip);
    int k = 1;
    #pragma unroll 1
    for (int c = 0; c < 7; ++c) {
        glayer<2>(k+0, fw, fb, gw, gb, rw, rb, h, skip);
        glayer<4>(k+1, fw, fb, gw, gb, rw, rb, h, skip);
        glayer<8>(k+2, fw, fb, gw, gb, rw, rb, h, skip);
        glayer<6>(k+3, fw, fb, gw, gb, rw, rb, h, skip);
        k += 4;
    }
    glayer<2>(29, fw, fb, gw, gb, rw, rb, h, skip);

    // epilogue: 1x1 convs + mu-law expand -> e = exp(v) kept in registers
    const float w1 = c1w[0], b1 = c1b[0], w2 = c2w[0], b2 = c2b[0];
    float s = 0.0f;
    #pragma unroll
    for (int j = 0; j < C; ++j) {
        float o = fmaf(fmaxf(skip[j], 0.0f), w1, b1);
        o = fmaf(fmaxf(o, 0.0f), w2, b2);
        const float a = fabsf(o);
        float v = (__expf(EIGHT_LN2 * a) - 1.0f) * (1.0f / 255.0f);
        v = copysignf(v, o);
        const float e = __expf(v);
        h[j] = e;                              // h dead; reuse for e
        const int i = l * C + j;
        const long long t = P0 + i;
        s += (i >= HALO && t < T_LEN) ? e : 0.0f;
    }
    #pragma unroll
    for (int off = 32; off >= 1; off >>= 1) s += __shfl_xor(s, off, 64);
    if (l == 0) partsum[gtile] = s;

    cg::this_grid().sync();

    // row sum (125 partials), uniform across wave after reduce
    float rs = (l < WPR) ? partsum[row * WPR + l] : 0.0f;
    if (l + 64 < WPR) rs += partsum[row * WPR + l + 64];
    #pragma unroll
    for (int off = 32; off >= 1; off >>= 1) rs += __shfl_xor(rs, off, 64);
    const float inv = 1.0f / rs;

    // scale in registers, transpose through LDS, coalesced store
    #pragma unroll
    for (int j = 0; j < C; ++j) slice[l * LDSP + j] = h[j] * inv;
    __syncthreads();
    float* orow = out + (size_t)row * T_LEN;
    #pragma unroll 1
    for (int it = 0; it < USEFUL / 64; ++it) {
        const int i = HALO + l + 64 * it;
        const long long t = P0 + i;
        if (t < T_LEN) orow[t] = stg[w][(i / C) * LDSP + (i % C)];
    }
}

// ---------------------------------------------------------------------------
extern "C" void kernel_launch(void* const* d_in, const int* in_sizes, int n_in,
                              void* d_out, int out_size, void* d_ws, size_t ws_size,
                              hipStream_t stream)
{
    const float* x   = (const float*)d_in[0];
    const float* cw  = (const float*)d_in[1];
    const float* cb  = (const float*)d_in[2];
    const float* fw  = (const float*)d_in[3];
    const float* fb  = (const float*)d_in[4];
    const float* gw  = (const float*)d_in[5];
    const float* gb  = (const float*)d_in[6];
    const float* rw  = (const float*)d_in[7];
    const float* rb  = (const float*)d_in[8];
    const float* c1w = (const float*)d_in[9];
    const float* c1b = (const float*)d_in[10];
    const float* c2w = (const float*)d_in[11];
    const float* c2b = (const float*)d_in[12];

    float* out     = (float*)d_out;
    float* partsum = (float*)d_ws;            // NWAVE = 1000 floats

    void* args[] = {
        (void*)&x, (void*)&cw, (void*)&cb, (void*)&fw, (void*)&fb,
        (void*)&gw, (void*)&gb, (void*)&rw, (void*)&rb,
        (void*)&c1w, (void*)&c1b, (void*)&c2w, (void*)&c2b,
        (void*)&out, (void*)&partsum
    };
    hipLaunchCooperativeKernel((void*)k_fused, dim3(NBLK), dim3(256),
                               args, 0, stream);
}

// Round 7
// 155.115 us; speedup vs baseline: 1.3165x; 1.3165x over previous
//
#include <hip/hip_runtime.h>
#include <cmath>

#define T_LEN 262144
#define NROW 8
#define NL 30
#define NT 512
#define PPT 4                        /* float2 pairs per thread */
#define EXT (NT * PPT * 2)           /* 4096 positions */
#define HALO 576
#define TILE (EXT - HALO)            /* 3520 */
#define PB ((T_LEN + TILE - 1) / TILE)   /* 75 tiles per row */
#define PAD 32
#define CH 4096                      /* elements per scale chunk */
#define RB (T_LEN / CH)              /* 64 chunks per row */
#define NB2 (NROW * RB)              /* 512 */

#define NEG2LOG2E -2.885390082f      /* -2*log2(e) */
#define NEGLOG2E  -1.4426950409f     /* -log2(e)  */

#if __has_builtin(__builtin_amdgcn_exp2f)
#define EXP2(x) __builtin_amdgcn_exp2f(x)
#else
#define EXP2(x) __expf(0.6931471805599453f * (x))
#endif

__device__ __forceinline__ float fast_rcp(float x) { return __builtin_amdgcn_rcpf(x); }

// progressive halo cut: positions < CUT[k] are dead at gated layer k
// CUT[k] = 576 - sum_{j>k} 4*d_j  (all even, monotone increasing)
__device__ const int c_cut[NL] = {
      8,  16,  32,  64,  88,  96, 112, 144, 168, 176,
    192, 224, 248, 256, 272, 304, 328, 336, 352, 384,
    408, 416, 432, 464, 488, 496, 512, 544, 568, 576};

// z = tanh(a)*sigmoid(g) = (1-u) / ((1+u)(1+w)), u=e^{-2a}, w=e^{-g}
__device__ __forceinline__ float gated(float af, float ag)
{
    const float u = EXP2(af * NEG2LOG2E);
    const float w = EXP2(ag * NEGLOG2E);
    return (1.0f - u) * fast_rcp((1.0f + u) * (1.0f + w));
}

// One gated residual layer over pairs; dilation D even (taps 8B-aligned).
// Ping-pong src->dst, one barrier. Center tap stays in registers.
// Pair 0 (i2 < 1024) is skipped once below the progressive cut.
template<int D>
__device__ __forceinline__ void layer_pair(
    int k, int cut,
    const float* __restrict__ fw, const float* __restrict__ fb,
    const float* __restrict__ gw, const float* __restrict__ gb,
    const float* __restrict__ rw, const float* __restrict__ rb,
    const float* __restrict__ src, float* __restrict__ dst,
    float2 (&h)[PPT], float2 (&skip)[PPT], int tid, bool writeback)
{
    const float f0 = fw[k*5+0], f1 = fw[k*5+1], f2 = fw[k*5+2], f3 = fw[k*5+3], f4 = fw[k*5+4];
    const float fbk = fb[k];
    const float g0 = gw[k*5+0], g1 = gw[k*5+1], g2 = gw[k*5+2], g3 = gw[k*5+3], g4 = gw[k*5+4];
    const float gbk = gb[k];
    const float rwk = rw[k], rbk = rb[k];

    #pragma unroll
    for (int p = 0; p < PPT; ++p) {
        const int i2 = 2 * (tid + p * NT);
        if (p == 0 && (i2 + 1) < cut) continue;   // dead halo pair (stays dead)

        const float2 v0 = *(const float2*)&src[i2 - 4*D];
        const float2 v1 = *(const float2*)&src[i2 - 3*D];
        const float2 v2 = *(const float2*)&src[i2 - 2*D];
        const float2 v3 = *(const float2*)&src[i2 -   D];
        const float2 v4 = h[p];

        float afx = fbk, afy = fbk;
        afx = fmaf(f0, v0.x, afx); afy = fmaf(f0, v0.y, afy);
        afx = fmaf(f1, v1.x, afx); afy = fmaf(f1, v1.y, afy);
        afx = fmaf(f2, v2.x, afx); afy = fmaf(f2, v2.y, afy);
        afx = fmaf(f3, v3.x, afx); afy = fmaf(f3, v3.y, afy);
        afx = fmaf(f4, v4.x, afx); afy = fmaf(f4, v4.y, afy);
        float agx = gbk, agy = gbk;
        agx = fmaf(g0, v0.x, agx); agy = fmaf(g0, v0.y, agy);
        agx = fmaf(g1, v1.x, agx); agy = fmaf(g1, v1.y, agy);
        agx = fmaf(g2, v2.x, agx); agy = fmaf(g2, v2.y, agy);
        agx = fmaf(g3, v3.x, agx); agy = fmaf(g3, v3.y, agy);
        agx = fmaf(g4, v4.x, agx); agy = fmaf(g4, v4.y, agy);

        const float zx = gated(afx, agx);
        const float zy = gated(afy, agy);
        skip[p].x += zx; skip[p].y += zy;
        h[p].x = fmaf(zx, rwk, rbk) + v4.x;
        h[p].y = fmaf(zy, rwk, rbk) + v4.y;
        if (writeback) *(float2*)&dst[i2] = h[p];
    }
    if (writeback) __syncthreads();
}

// d=1 gated layer (layer 0): odd tap offsets -> use neighbor pair values.
__device__ __forceinline__ void layer_pair_d1(
    int k,
    const float* __restrict__ fw, const float* __restrict__ fb,
    const float* __restrict__ gw, const float* __restrict__ gb,
    const float* __restrict__ rw, const float* __restrict__ rb,
    const float* __restrict__ src, float* __restrict__ dst,
    float2 (&h)[PPT], float2 (&skip)[PPT], int tid)
{
    const float f0 = fw[k*5+0], f1 = fw[k*5+1], f2 = fw[k*5+2], f3 = fw[k*5+3], f4 = fw[k*5+4];
    const float fbk = fb[k];
    const float g0 = gw[k*5+0], g1 = gw[k*5+1], g2 = gw[k*5+2], g3 = gw[k*5+3], g4 = gw[k*5+4];
    const float gbk = gb[k];
    const float rwk = rw[k], rbk = rb[k];

    #pragma unroll
    for (int p = 0; p < PPT; ++p) {
        const int i2 = 2 * (tid + p * NT);
        const float2 a = *(const float2*)&src[i2 - 4];
        const float2 b = *(const float2*)&src[i2 - 2];
        const float2 c = h[p];

        float afx = fbk, afy = fbk, agx = gbk, agy = gbk;
        afx = fmaf(f0, a.x, afx); afy = fmaf(f0, a.y, afy);
        afx = fmaf(f1, a.y, afx); afy = fmaf(f1, b.x, afy);
        afx = fmaf(f2, b.x, afx); afy = fmaf(f2, b.y, afy);
        afx = fmaf(f3, b.y, afx); afy = fmaf(f3, c.x, afy);
        afx = fmaf(f4, c.x, afx); afy = fmaf(f4, c.y, afy);
        agx = fmaf(g0, a.x, agx); agy = fmaf(g0, a.y, agy);
        agx = fmaf(g1, a.y, agx); agy = fmaf(g1, b.x, agy);
        agx = fmaf(g2, b.x, agx); agy = fmaf(g2, b.y, agy);
        agx = fmaf(g3, b.y, agx); agy = fmaf(g3, c.x, agy);
        agx = fmaf(g4, c.x, agx); agy = fmaf(g4, c.y, agy);

        const float zx = gated(afx, agx);
        const float zy = gated(afy, agy);
        skip[p].x += zx; skip[p].y += zy;
        h[p].x = fmaf(zx, rwk, rbk) + c.x;
        h[p].y = fmaf(zy, rwk, rbk) + c.y;
        *(float2*)&dst[i2] = h[p];
    }
    __syncthreads();
}

// ---------------------------------------------------------------------------
__global__ __launch_bounds__(NT, 8)
void k_wavenet(const float* __restrict__ x,
               const float* __restrict__ cw,  const float* __restrict__ cb,
               const float* __restrict__ fw,  const float* __restrict__ fb,
               const float* __restrict__ gw,  const float* __restrict__ gb,
               const float* __restrict__ rw,  const float* __restrict__ rb,
               const float* __restrict__ c1w, const float* __restrict__ c1b,
               const float* __restrict__ c2w, const float* __restrict__ c2b,
               float* __restrict__ eout, float* __restrict__ partsum)
{
    __shared__ float hrawA[PAD + EXT];
    __shared__ float hrawB[PAD + EXT];
    __shared__ float reds[NT / 64];
    float* bufA = hrawA + PAD;
    float* bufB = hrawB + PAD;

    const int tid  = threadIdx.x;
    const int row  = blockIdx.x / PB;
    const int tile = blockIdx.x % PB;
    const int t0   = tile * TILE;

    if (tid < PAD) { hrawA[tid] = 0.0f; hrawB[tid] = 0.0f; }

    const float* xr = x + (size_t)row * T_LEN;
    float2 h[PPT], skip[PPT];
    #pragma unroll
    for (int p = 0; p < PPT; ++p) {
        const int i2 = 2 * (tid + p * NT);
        const int g = t0 - HALO + i2;
        float2 v;
        v.x = (g     >= 0 && g     < T_LEN) ? xr[g]     : 0.0f;
        v.y = (g + 1 >= 0 && g + 1 < T_LEN) ? xr[g + 1] : 0.0f;
        *(float2*)&bufA[i2] = v;
        h[p] = v;
        skip[p].x = 0.0f; skip[p].y = 0.0f;
    }
    __syncthreads();

    // initial causal conv (d=1): A -> B
    {
        const float w0 = cw[0], w1 = cw[1], w2 = cw[2], w3 = cw[3], w4 = cw[4];
        const float b  = cb[0];
        #pragma unroll
        for (int p = 0; p < PPT; ++p) {
            const int i2 = 2 * (tid + p * NT);
            const float2 a = *(const float2*)&bufA[i2 - 4];
            const float2 bb = *(const float2*)&bufA[i2 - 2];
            const float2 c = h[p];
            float ax = b, ay = b;
            ax = fmaf(w0, a.x, ax);  ay = fmaf(w0, a.y, ay);
            ax = fmaf(w1, a.y, ax);  ay = fmaf(w1, bb.x, ay);
            ax = fmaf(w2, bb.x, ax); ay = fmaf(w2, bb.y, ay);
            ax = fmaf(w3, bb.y, ax); ay = fmaf(w3, c.x, ay);
            ax = fmaf(w4, c.x, ax);  ay = fmaf(w4, c.y, ay);
            h[p].x = ax; h[p].y = ay;
        }
        #pragma unroll
        for (int p = 0; p < PPT; ++p)
            *(float2*)&bufB[2 * (tid + p * NT)] = h[p];
        __syncthreads();
    }

    // layer 0 (d=1): B -> A, then 7 x (2,4,8,6), then final d=2 (no writeback)
    layer_pair_d1(0, fw, fb, gw, gb, rw, rb, bufB, bufA, h, skip, tid);
    int k = 1;
    #pragma unroll 1
    for (int c = 0; c < 7; ++c) {
        layer_pair<2>(k+0, c_cut[k+0], fw, fb, gw, gb, rw, rb, bufA, bufB, h, skip, tid, true);
        layer_pair<4>(k+1, c_cut[k+1], fw, fb, gw, gb, rw, rb, bufB, bufA, h, skip, tid, true);
        layer_pair<8>(k+2, c_cut[k+2], fw, fb, gw, gb, rw, rb, bufA, bufB, h, skip, tid, true);
        layer_pair<6>(k+3, c_cut[k+3], fw, fb, gw, gb, rw, rb, bufB, bufA, h, skip, tid, true);
        k += 4;
    }
    layer_pair<2>(29, c_cut[29], fw, fb, gw, gb, rw, rb, bufA, bufB, h, skip, tid, false);

    // epilogue: 1x1 convs + mu-law expand; write e = exp(v); partial sum
    const float w1 = c1w[0], b1 = c1b[0], w2 = c2w[0], b2 = c2b[0];
    float s = 0.0f;
    float* er = eout + (size_t)row * T_LEN;
    #pragma unroll
    for (int p = 0; p < PPT; ++p) {
        const int i2 = 2 * (tid + p * NT);
        if (i2 >= HALO) {
            const int t = t0 + i2 - HALO;
            if (t < T_LEN) {
                float ox = fmaf(fmaxf(skip[p].x, 0.0f), w1, b1);
                float oy = fmaf(fmaxf(skip[p].y, 0.0f), w1, b1);
                ox = fmaf(fmaxf(ox, 0.0f), w2, b2);
                oy = fmaf(fmaxf(oy, 0.0f), w2, b2);
                float vx = fmaf(EXP2(8.0f * fabsf(ox)), (1.0f/255.0f), -(1.0f/255.0f));
                float vy = fmaf(EXP2(8.0f * fabsf(oy)), (1.0f/255.0f), -(1.0f/255.0f));
                vx = copysignf(vx, ox);
                vy = copysignf(vy, oy);
                const float ex = __expf(vx);
                const float ey = __expf(vy);
                float2 e; e.x = ex; e.y = ey;
                *(float2*)&er[t] = e;
                s += ex + ey;
            }
        }
    }
    #pragma unroll
    for (int off = 32; off >= 1; off >>= 1) s += __shfl_xor(s, off, 64);
    if ((tid & 63) == 0) reds[tid >> 6] = s;
    __syncthreads();
    if (tid == 0) {
        float ss = 0.0f;
        #pragma unroll
        for (int w = 0; w < NT / 64; ++w) ss += reds[w];
        partsum[blockIdx.x] = ss;
    }
}

// ---------------------------------------------------------------------------
__global__ __launch_bounds__(256)
void k_scale(float* __restrict__ ebuf, const float* __restrict__ partsum)
{
    const int tid = threadIdx.x;
    const int row = blockIdx.x / RB;

    __shared__ float red[4];
    float s = 0.0f;
    for (int j = tid; j < PB; j += 256) s += partsum[row * PB + j];
    #pragma unroll
    for (int off = 32; off >= 1; off >>= 1) s += __shfl_xor(s, off, 64);
    if ((tid & 63) == 0) red[tid >> 6] = s;
    __syncthreads();
    const float tot = (red[0] + red[1]) + (red[2] + red[3]);
    const float inv = 1.0f / tot;

    float4* vp = (float4*)(ebuf + (size_t)blockIdx.x * CH);
    #pragma unroll
    for (int q = 0; q < 4; ++q) {
        float4 v = vp[tid + q * 256];
        v.x *= inv; v.y *= inv; v.z *= inv; v.w *= inv;
        vp[tid + q * 256] = v;
    }
}

// ---------------------------------------------------------------------------
extern "C" void kernel_launch(void* const* d_in, const int* in_sizes, int n_in,
                              void* d_out, int out_size, void* d_ws, size_t ws_size,
                              hipStream_t stream)
{
    const float* x   = (const float*)d_in[0];
    const float* cw  = (const float*)d_in[1];
    const float* cb  = (const float*)d_in[2];
    const float* fw  = (const float*)d_in[3];
    const float* fb  = (const float*)d_in[4];
    const float* gw  = (const float*)d_in[5];
    const float* gb  = (const float*)d_in[6];
    const float* rw  = (const float*)d_in[7];
    const float* rb  = (const float*)d_in[8];
    const float* c1w = (const float*)d_in[9];
    const float* c1b = (const float*)d_in[10];
    const float* c2w = (const float*)d_in[11];
    const float* c2b = (const float*)d_in[12];

    float* eout    = (float*)d_out;
    float* partsum = (float*)d_ws;            // NROW*PB = 600 floats

    k_wavenet<<<NROW * PB, NT, 0, stream>>>(x, cw, cb, fw, fb, gw, gb, rw, rb,
                                            c1w, c1b, c2w, c2b, eout, partsum);
    k_scale<<<NB2, 256, 0, stream>>>(eout, partsum);
}

// Round 8
// 145.418 us; speedup vs baseline: 1.4043x; 1.0667x over previous
//
#include <hip/hip_runtime.h>
#include <cmath>

#define T_LEN 262144
#define NROW 8
#define NL 30
#define NT 256
#define PPT 6                        /* f32x2 pairs per thread */
#define EXT (NT * PPT * 2)           /* 3072 positions */
#define HALO 576
#define TILE (EXT - HALO)            /* 2496 */
#define PB ((T_LEN + TILE - 1) / TILE)   /* 106 tiles per row */
#define PAD 32
#define CH 4096                      /* elements per scale chunk */
#define RB (T_LEN / CH)              /* 64 chunks per row */
#define NB2 (NROW * RB)              /* 512 */

#define NEG2LOG2E -2.885390082f      /* -2*log2(e) */
#define NEGLOG2E  -1.4426950409f     /* -log2(e)  */

#if __has_builtin(__builtin_amdgcn_exp2f)
#define EXP2(x) __builtin_amdgcn_exp2f(x)
#else
#define EXP2(x) __expf(0.6931471805599453f * (x))
#endif

typedef float f32x2 __attribute__((ext_vector_type(2)));

__device__ __forceinline__ float fast_rcp(float x) { return __builtin_amdgcn_rcpf(x); }

__device__ __forceinline__ f32x2 exp2v(f32x2 x) {
    f32x2 r; r.x = EXP2(x.x); r.y = EXP2(x.y); return r;
}
__device__ __forceinline__ f32x2 rcpv(f32x2 x) {
    f32x2 r; r.x = fast_rcp(x.x); r.y = fast_rcp(x.y); return r;
}

// One gated residual layer over f32x2 pairs (packed fp32 math).
// D = dilation (even), CUT = progressive dead-halo bound (compile-time),
// WB = write result to dst + barrier. k passed as literal at each call site.
template<int D, int CUT, bool WB>
__device__ __forceinline__ void layerv(
    int k,
    const float* __restrict__ fw, const float* __restrict__ fb,
    const float* __restrict__ gw, const float* __restrict__ gb,
    const float* __restrict__ rw, const float* __restrict__ rb,
    const float* __restrict__ src, float* __restrict__ dst,
    f32x2 (&h)[PPT], f32x2 (&skip)[PPT], int tid)
{
    const float f0 = fw[k*5+0], f1 = fw[k*5+1], f2 = fw[k*5+2], f3 = fw[k*5+3], f4 = fw[k*5+4];
    const float fbk = fb[k];
    const float g0 = gw[k*5+0], g1 = gw[k*5+1], g2 = gw[k*5+2], g3 = gw[k*5+3], g4 = gw[k*5+4];
    const float gbk = gb[k];
    const float rwk = rw[k], rbk = rb[k];

    #pragma unroll
    for (int p = 0; p < PPT; ++p) {
        const int i2 = 2 * (tid + p * NT);
        if (2 * p * NT < CUT) {               // only pairs that can be dead
            if ((i2 + 1) < CUT) continue;     // dead halo pair (stays dead)
        }

        const f32x2 v0 = *(const f32x2*)&src[i2 - 4*D];
        const f32x2 v1 = *(const f32x2*)&src[i2 - 3*D];
        const f32x2 v2 = *(const f32x2*)&src[i2 - 2*D];
        const f32x2 v3 = *(const f32x2*)&src[i2 -   D];
        const f32x2 v4 = h[p];

        f32x2 af = fbk + f0 * v0;
        af = f1 * v1 + af;
        af = f2 * v2 + af;
        af = f3 * v3 + af;
        af = f4 * v4 + af;
        f32x2 ag = gbk + g0 * v0;
        ag = g1 * v1 + ag;
        ag = g2 * v2 + ag;
        ag = g3 * v3 + ag;
        ag = g4 * v4 + ag;

        // z = tanh(af)*sigmoid(ag) = (1-u)/((1+u)(1+w)), u=e^{-2af}, w=e^{-ag}
        const f32x2 u = exp2v(af * NEG2LOG2E);
        const f32x2 w = exp2v(ag * NEGLOG2E);
        const f32x2 num = 1.0f - u;
        const f32x2 den = (1.0f + u) * (1.0f + w);
        const f32x2 z = num * rcpv(den);
        skip[p] += z;
        if (WB) {
            h[p] = (z * rwk + rbk) + v4;
            *(f32x2*)&dst[i2] = h[p];
        }
    }
    if (WB) __syncthreads();
}

// d=1 gated layer (layer 0): odd tap offsets -> neighbor-component shuffles.
__device__ __forceinline__ void layer_d1(
    const float* __restrict__ fw, const float* __restrict__ fb,
    const float* __restrict__ gw, const float* __restrict__ gb,
    const float* __restrict__ rw, const float* __restrict__ rb,
    const float* __restrict__ src, float* __restrict__ dst,
    f32x2 (&h)[PPT], f32x2 (&skip)[PPT], int tid)
{
    const float f0 = fw[0], f1 = fw[1], f2 = fw[2], f3 = fw[3], f4 = fw[4];
    const float fbk = fb[0];
    const float g0 = gw[0], g1 = gw[1], g2 = gw[2], g3 = gw[3], g4 = gw[4];
    const float gbk = gb[0];
    const float rwk = rw[0], rbk = rb[0];

    #pragma unroll
    for (int p = 0; p < PPT; ++p) {
        const int i2 = 2 * (tid + p * NT);
        const f32x2 a = *(const f32x2*)&src[i2 - 4];
        const f32x2 b = *(const f32x2*)&src[i2 - 2];
        const f32x2 c = h[p];
        f32x2 v0, v1, v2, v3;
        v0.x = a.x; v0.y = a.y;
        v1.x = a.y; v1.y = b.x;
        v2.x = b.x; v2.y = b.y;
        v3.x = b.y; v3.y = c.x;

        f32x2 af = fbk + f0 * v0;
        af = f1 * v1 + af;
        af = f2 * v2 + af;
        af = f3 * v3 + af;
        af = f4 * c  + af;
        f32x2 ag = gbk + g0 * v0;
        ag = g1 * v1 + ag;
        ag = g2 * v2 + ag;
        ag = g3 * v3 + ag;
        ag = g4 * c  + ag;

        const f32x2 u = exp2v(af * NEG2LOG2E);
        const f32x2 w = exp2v(ag * NEGLOG2E);
        const f32x2 num = 1.0f - u;
        const f32x2 den = (1.0f + u) * (1.0f + w);
        const f32x2 z = num * rcpv(den);
        skip[p] += z;
        h[p] = (z * rwk + rbk) + c;
        *(f32x2*)&dst[i2] = h[p];
    }
    __syncthreads();
}

// ---------------------------------------------------------------------------
__global__ __launch_bounds__(NT, 6)
void k_wavenet(const float* __restrict__ x,
               const float* __restrict__ cw,  const float* __restrict__ cb,
               const float* __restrict__ fw,  const float* __restrict__ fb,
               const float* __restrict__ gw,  const float* __restrict__ gb,
               const float* __restrict__ rw,  const float* __restrict__ rb,
               const float* __restrict__ c1w, const float* __restrict__ c1b,
               const float* __restrict__ c2w, const float* __restrict__ c2b,
               float* __restrict__ eout, float* __restrict__ partsum)
{
    __shared__ __align__(16) float hrawA[PAD + EXT];
    __shared__ __align__(16) float hrawB[PAD + EXT];
    __shared__ float reds[NT / 64];
    float* bufA = hrawA + PAD;
    float* bufB = hrawB + PAD;

    const int tid  = threadIdx.x;
    const int row  = blockIdx.x / PB;
    const int tile = blockIdx.x % PB;
    const int t0   = tile * TILE;

    if (tid < PAD) { hrawA[tid] = 0.0f; hrawB[tid] = 0.0f; }

    const float* xr = x + (size_t)row * T_LEN;
    f32x2 h[PPT], skip[PPT];
    #pragma unroll
    for (int p = 0; p < PPT; ++p) {
        const int i2 = 2 * (tid + p * NT);
        const int g = t0 - HALO + i2;
        f32x2 v;
        v.x = (g     >= 0 && g     < T_LEN) ? xr[g]     : 0.0f;
        v.y = (g + 1 >= 0 && g + 1 < T_LEN) ? xr[g + 1] : 0.0f;
        *(f32x2*)&bufA[i2] = v;
        h[p] = v;
        skip[p].x = 0.0f; skip[p].y = 0.0f;
    }
    __syncthreads();

    // initial causal conv (d=1): A -> B
    {
        const float w0 = cw[0], w1 = cw[1], w2 = cw[2], w3 = cw[3], w4 = cw[4];
        const float b  = cb[0];
        #pragma unroll
        for (int p = 0; p < PPT; ++p) {
            const int i2 = 2 * (tid + p * NT);
            const f32x2 a  = *(const f32x2*)&bufA[i2 - 4];
            const f32x2 bb = *(const f32x2*)&bufA[i2 - 2];
            const f32x2 c  = h[p];
            f32x2 v0, v1, v2, v3;
            v0.x = a.x;  v0.y = a.y;
            v1.x = a.y;  v1.y = bb.x;
            v2.x = bb.x; v2.y = bb.y;
            v3.x = bb.y; v3.y = c.x;
            f32x2 acc = b + w0 * v0;
            acc = w1 * v1 + acc;
            acc = w2 * v2 + acc;
            acc = w3 * v3 + acc;
            acc = w4 * c  + acc;
            h[p] = acc;
            *(f32x2*)&bufB[i2] = acc;
        }
        __syncthreads();
    }

    // 30 layers, fully unrolled; ping-pong B->A->B...; literal k and CUT.
    layer_d1(fw, fb, gw, gb, rw, rb, bufB, bufA, h, skip, tid);
    layerv<2,  16, true >( 1, fw, fb, gw, gb, rw, rb, bufA, bufB, h, skip, tid);
    layerv<4,  32, true >( 2, fw, fb, gw, gb, rw, rb, bufB, bufA, h, skip, tid);
    layerv<8,  64, true >( 3, fw, fb, gw, gb, rw, rb, bufA, bufB, h, skip, tid);
    layerv<6,  88, true >( 4, fw, fb, gw, gb, rw, rb, bufB, bufA, h, skip, tid);
    layerv<2,  96, true >( 5, fw, fb, gw, gb, rw, rb, bufA, bufB, h, skip, tid);
    layerv<4, 112, true >( 6, fw, fb, gw, gb, rw, rb, bufB, bufA, h, skip, tid);
    layerv<8, 144, true >( 7, fw, fb, gw, gb, rw, rb, bufA, bufB, h, skip, tid);
    layerv<6, 168, true >( 8, fw, fb, gw, gb, rw, rb, bufB, bufA, h, skip, tid);
    layerv<2, 176, true >( 9, fw, fb, gw, gb, rw, rb, bufA, bufB, h, skip, tid);
    layerv<4, 192, true >(10, fw, fb, gw, gb, rw, rb, bufB, bufA, h, skip, tid);
    layerv<8, 224, true >(11, fw, fb, gw, gb, rw, rb, bufA, bufB, h, skip, tid);
    layerv<6, 248, true >(12, fw, fb, gw, gb, rw, rb, bufB, bufA, h, skip, tid);
    layerv<2, 256, true >(13, fw, fb, gw, gb, rw, rb, bufA, bufB, h, skip, tid);
    layerv<4, 272, true >(14, fw, fb, gw, gb, rw, rb, bufB, bufA, h, skip, tid);
    layerv<8, 304, true >(15, fw, fb, gw, gb, rw, rb, bufA, bufB, h, skip, tid);
    layerv<6, 328, true >(16, fw, fb, gw, gb, rw, rb, bufB, bufA, h, skip, tid);
    layerv<2, 336, true >(17, fw, fb, gw, gb, rw, rb, bufA, bufB, h, skip, tid);
    layerv<4, 352, true >(18, fw, fb, gw, gb, rw, rb, bufB, bufA, h, skip, tid);
    layerv<8, 384, true >(19, fw, fb, gw, gb, rw, rb, bufA, bufB, h, skip, tid);
    layerv<6, 408, true >(20, fw, fb, gw, gb, rw, rb, bufB, bufA, h, skip, tid);
    layerv<2, 416, true >(21, fw, fb, gw, gb, rw, rb, bufA, bufB, h, skip, tid);
    layerv<4, 432, true >(22, fw, fb, gw, gb, rw, rb, bufB, bufA, h, skip, tid);
    layerv<8, 464, true >(23, fw, fb, gw, gb, rw, rb, bufA, bufB, h, skip, tid);
    layerv<6, 488, true >(24, fw, fb, gw, gb, rw, rb, bufB, bufA, h, skip, tid);
    layerv<2, 496, true >(25, fw, fb, gw, gb, rw, rb, bufA, bufB, h, skip, tid);
    layerv<4, 512, true >(26, fw, fb, gw, gb, rw, rb, bufB, bufA, h, skip, tid);
    layerv<8, 544, true >(27, fw, fb, gw, gb, rw, rb, bufA, bufB, h, skip, tid);
    layerv<6, 568, true >(28, fw, fb, gw, gb, rw, rb, bufB, bufA, h, skip, tid);
    layerv<2, 576, false>(29, fw, fb, gw, gb, rw, rb, bufA, bufB, h, skip, tid);

    // epilogue: 1x1 convs + mu-law expand; write e = exp(v); partial sum
    const float w1 = c1w[0], b1 = c1b[0], w2 = c2w[0], b2 = c2b[0];
    float s = 0.0f;
    float* er = eout + (size_t)row * T_LEN;
    #pragma unroll
    for (int p = 0; p < PPT; ++p) {
        const int i2 = 2 * (tid + p * NT);
        if (i2 >= HALO) {
            const int t = t0 + i2 - HALO;
            if (t < T_LEN) {
                f32x2 sk = skip[p];
                float ox = fmaf(fmaxf(sk.x, 0.0f), w1, b1);
                float oy = fmaf(fmaxf(sk.y, 0.0f), w1, b1);
                ox = fmaf(fmaxf(ox, 0.0f), w2, b2);
                oy = fmaf(fmaxf(oy, 0.0f), w2, b2);
                float vx = fmaf(EXP2(8.0f * fabsf(ox)), (1.0f/255.0f), -(1.0f/255.0f));
                float vy = fmaf(EXP2(8.0f * fabsf(oy)), (1.0f/255.0f), -(1.0f/255.0f));
                vx = copysignf(vx, ox);
                vy = copysignf(vy, oy);
                const float ex = __expf(vx);
                const float ey = __expf(vy);
                f32x2 e; e.x = ex; e.y = ey;
                *(f32x2*)&er[t] = e;
                s += ex + ey;
            }
        }
    }
    #pragma unroll
    for (int off = 32; off >= 1; off >>= 1) s += __shfl_xor(s, off, 64);
    if ((tid & 63) == 0) reds[tid >> 6] = s;
    __syncthreads();
    if (tid == 0) {
        float ss = 0.0f;
        #pragma unroll
        for (int w = 0; w < NT / 64; ++w) ss += reds[w];
        partsum[blockIdx.x] = ss;
    }
}

// ---------------------------------------------------------------------------
__global__ __launch_bounds__(256)
void k_scale(float* __restrict__ ebuf, const float* __restrict__ partsum)
{
    const int tid = threadIdx.x;
    const int row = blockIdx.x / RB;

    __shared__ float red[4];
    float s = 0.0f;
    for (int j = tid; j < PB; j += 256) s += partsum[row * PB + j];
    #pragma unroll
    for (int off = 32; off >= 1; off >>= 1) s += __shfl_xor(s, off, 64);
    if ((tid & 63) == 0) red[tid >> 6] = s;
    __syncthreads();
    const float tot = (red[0] + red[1]) + (red[2] + red[3]);
    const float inv = 1.0f / tot;

    float4* vp = (float4*)(ebuf + (size_t)blockIdx.x * CH);
    #pragma unroll
    for (int q = 0; q < 4; ++q) {
        float4 v = vp[tid + q * 256];
        v.x *= inv; v.y *= inv; v.z *= inv; v.w *= inv;
        vp[tid + q * 256] = v;
    }
}

// ---------------------------------------------------------------------------
extern "C" void kernel_launch(void* const* d_in, const int* in_sizes, int n_in,
                              void* d_out, int out_size, void* d_ws, size_t ws_size,
                              hipStream_t stream)
{
    const float* x   = (const float*)d_in[0];
    const float* cw  = (const float*)d_in[1];
    const float* cb  = (const float*)d_in[2];
    const float* fw  = (const float*)d_in[3];
    const float* fb  = (const float*)d_in[4];
    const float* gw  = (const float*)d_in[5];
    const float* gb  = (const float*)d_in[6];
    const float* rw  = (const float*)d_in[7];
    const float* rb  = (const float*)d_in[8];
    const float* c1w = (const float*)d_in[9];
    const float* c1b = (const float*)d_in[10];
    const float* c2w = (const float*)d_in[11];
    const float* c2b = (const float*)d_in[12];

    float* eout    = (float*)d_out;
    float* partsum = (float*)d_ws;            // NROW*PB = 848 floats

    k_wavenet<<<NROW * PB, NT, 0, stream>>>(x, cw, cb, fw, fb, gw, gb, rw, rb,
                                            c1w, c1b, c2w, c2b, eout, partsum);
    k_scale<<<NB2, 256, 0, stream>>>(eout, partsum);
}

// Round 9
// 144.317 us; speedup vs baseline: 1.4150x; 1.0076x over previous
//
#include <hip/hip_runtime.h>
#include <cmath>

#define T_LEN 262144
#define NROW 8
#define NL 30
#define NT 512
#define PPT 3                        /* f32x2 pairs per thread */
#define EXT (NT * PPT * 2)           /* 3072 positions */
#define HALO 576
#define TILE (EXT - HALO)            /* 2496 */
#define PB ((T_LEN + TILE - 1) / TILE)   /* 106 tiles per row */
#define PAD 32
#define CH 4096                      /* elements per scale chunk */
#define RB (T_LEN / CH)              /* 64 chunks per row */
#define NB2 (NROW * RB)              /* 512 */

#define NEG2LOG2E -2.885390082f      /* -2*log2(e) */
#define NEGLOG2E  -1.4426950409f     /* -log2(e)  */

#if __has_builtin(__builtin_amdgcn_exp2f)
#define EXP2(x) __builtin_amdgcn_exp2f(x)
#else
#define EXP2(x) __expf(0.6931471805599453f * (x))
#endif

typedef float f32x2 __attribute__((ext_vector_type(2)));

__device__ __forceinline__ float fast_rcp(float x) { return __builtin_amdgcn_rcpf(x); }

__device__ __forceinline__ f32x2 exp2v(f32x2 x) {
    f32x2 r; r.x = EXP2(x.x); r.y = EXP2(x.y); return r;
}
__device__ __forceinline__ f32x2 rcpv(f32x2 x) {
    f32x2 r; r.x = fast_rcp(x.x); r.y = fast_rcp(x.y); return r;
}

// One gated residual layer over f32x2 pairs (packed fp32 math).
// D = dilation (even), CUT = progressive dead-halo bound (compile-time),
// WB = write result to dst + barrier. k passed as literal at each call site.
template<int D, int CUT, bool WB>
__device__ __forceinline__ void layerv(
    int k,
    const float* __restrict__ fw, const float* __restrict__ fb,
    const float* __restrict__ gw, const float* __restrict__ gb,
    const float* __restrict__ rw, const float* __restrict__ rb,
    const float* __restrict__ src, float* __restrict__ dst,
    f32x2 (&h)[PPT], f32x2 (&skip)[PPT], int tid)
{
    const float f0 = fw[k*5+0], f1 = fw[k*5+1], f2 = fw[k*5+2], f3 = fw[k*5+3], f4 = fw[k*5+4];
    const float fbk = fb[k];
    const float g0 = gw[k*5+0], g1 = gw[k*5+1], g2 = gw[k*5+2], g3 = gw[k*5+3], g4 = gw[k*5+4];
    const float gbk = gb[k];
    const float rwk = rw[k], rbk = rb[k];

    #pragma unroll
    for (int p = 0; p < PPT; ++p) {
        const int i2 = 2 * (tid + p * NT);
        if (2 * p * NT < CUT) {               // only pairs that can be dead
            if ((i2 + 1) < CUT) continue;     // dead halo pair (stays dead)
        }

        const f32x2 v0 = *(const f32x2*)&src[i2 - 4*D];
        const f32x2 v1 = *(const f32x2*)&src[i2 - 3*D];
        const f32x2 v2 = *(const f32x2*)&src[i2 - 2*D];
        const f32x2 v3 = *(const f32x2*)&src[i2 -   D];
        const f32x2 v4 = h[p];

        f32x2 af = fbk + f0 * v0;
        af = f1 * v1 + af;
        af = f2 * v2 + af;
        af = f3 * v3 + af;
        af = f4 * v4 + af;
        f32x2 ag = gbk + g0 * v0;
        ag = g1 * v1 + ag;
        ag = g2 * v2 + ag;
        ag = g3 * v3 + ag;
        ag = g4 * v4 + ag;

        // z = tanh(af)*sigmoid(ag) = (1-u)/((1+u)(1+w)), u=e^{-2af}, w=e^{-ag}
        const f32x2 u = exp2v(af * NEG2LOG2E);
        const f32x2 w = exp2v(ag * NEGLOG2E);
        const f32x2 num = 1.0f - u;
        const f32x2 den = (1.0f + u) * (1.0f + w);
        const f32x2 z = num * rcpv(den);
        skip[p] += z;
        if (WB) {
            h[p] = (z * rwk + rbk) + v4;
            *(f32x2*)&dst[i2] = h[p];
        }
    }
    if (WB) __syncthreads();
}

// d=1 gated layer (layer 0): odd tap offsets -> neighbor-component shuffles.
__device__ __forceinline__ void layer_d1(
    const float* __restrict__ fw, const float* __restrict__ fb,
    const float* __restrict__ gw, const float* __restrict__ gb,
    const float* __restrict__ rw, const float* __restrict__ rb,
    const float* __restrict__ src, float* __restrict__ dst,
    f32x2 (&h)[PPT], f32x2 (&skip)[PPT], int tid)
{
    const float f0 = fw[0], f1 = fw[1], f2 = fw[2], f3 = fw[3], f4 = fw[4];
    const float fbk = fb[0];
    const float g0 = gw[0], g1 = gw[1], g2 = gw[2], g3 = gw[3], g4 = gw[4];
    const float gbk = gb[0];
    const float rwk = rw[0], rbk = rb[0];

    #pragma unroll
    for (int p = 0; p < PPT; ++p) {
        const int i2 = 2 * (tid + p * NT);
        const f32x2 a = *(const f32x2*)&src[i2 - 4];
        const f32x2 b = *(const f32x2*)&src[i2 - 2];
        const f32x2 c = h[p];
        f32x2 v0, v1, v2, v3;
        v0.x = a.x; v0.y = a.y;
        v1.x = a.y; v1.y = b.x;
        v2.x = b.x; v2.y = b.y;
        v3.x = b.y; v3.y = c.x;

        f32x2 af = fbk + f0 * v0;
        af = f1 * v1 + af;
        af = f2 * v2 + af;
        af = f3 * v3 + af;
        af = f4 * c  + af;
        f32x2 ag = gbk + g0 * v0;
        ag = g1 * v1 + ag;
        ag = g2 * v2 + ag;
        ag = g3 * v3 + ag;
        ag = g4 * c  + ag;

        const f32x2 u = exp2v(af * NEG2LOG2E);
        const f32x2 w = exp2v(ag * NEGLOG2E);
        const f32x2 num = 1.0f - u;
        const f32x2 den = (1.0f + u) * (1.0f + w);
        const f32x2 z = num * rcpv(den);
        skip[p] += z;
        h[p] = (z * rwk + rbk) + c;
        *(f32x2*)&dst[i2] = h[p];
    }
    __syncthreads();
}

// ---------------------------------------------------------------------------
__global__ __launch_bounds__(NT, 8)
void k_wavenet(const float* __restrict__ x,
               const float* __restrict__ cw,  const float* __restrict__ cb,
               const float* __restrict__ fw,  const float* __restrict__ fb,
               const float* __restrict__ gw,  const float* __restrict__ gb,
               const float* __restrict__ rw,  const float* __restrict__ rb,
               const float* __restrict__ c1w, const float* __restrict__ c1b,
               const float* __restrict__ c2w, const float* __restrict__ c2b,
               float* __restrict__ eout, float* __restrict__ partsum)
{
    __shared__ __align__(16) float hrawA[PAD + EXT];
    __shared__ __align__(16) float hrawB[PAD + EXT];
    __shared__ float reds[NT / 64];
    float* bufA = hrawA + PAD;
    float* bufB = hrawB + PAD;

    const int tid  = threadIdx.x;
    const int row  = blockIdx.x / PB;
    const int tile = blockIdx.x % PB;
    const int t0   = tile * TILE;

    if (tid < PAD) { hrawA[tid] = 0.0f; hrawB[tid] = 0.0f; }

    const float* xr = x + (size_t)row * T_LEN;
    f32x2 h[PPT], skip[PPT];
    #pragma unroll
    for (int p = 0; p < PPT; ++p) {
        const int i2 = 2 * (tid + p * NT);
        const int g = t0 - HALO + i2;
        f32x2 v;
        v.x = (g     >= 0 && g     < T_LEN) ? xr[g]     : 0.0f;
        v.y = (g + 1 >= 0 && g + 1 < T_LEN) ? xr[g + 1] : 0.0f;
        *(f32x2*)&bufA[i2] = v;
        h[p] = v;
        skip[p].x = 0.0f; skip[p].y = 0.0f;
    }
    __syncthreads();

    // initial causal conv (d=1): A -> B
    {
        const float w0 = cw[0], w1 = cw[1], w2 = cw[2], w3 = cw[3], w4 = cw[4];
        const float b  = cb[0];
        #pragma unroll
        for (int p = 0; p < PPT; ++p) {
            const int i2 = 2 * (tid + p * NT);
            const f32x2 a  = *(const f32x2*)&bufA[i2 - 4];
            const f32x2 bb = *(const f32x2*)&bufA[i2 - 2];
            const f32x2 c  = h[p];
            f32x2 v0, v1, v2, v3;
            v0.x = a.x;  v0.y = a.y;
            v1.x = a.y;  v1.y = bb.x;
            v2.x = bb.x; v2.y = bb.y;
            v3.x = bb.y; v3.y = c.x;
            f32x2 acc = b + w0 * v0;
            acc = w1 * v1 + acc;
            acc = w2 * v2 + acc;
            acc = w3 * v3 + acc;
            acc = w4 * c  + acc;
            h[p] = acc;
            *(f32x2*)&bufB[i2] = acc;
        }
        __syncthreads();
    }

    // 30 layers, fully unrolled; ping-pong B->A->B...; literal k and CUT.
    layer_d1(fw, fb, gw, gb, rw, rb, bufB, bufA, h, skip, tid);
    layerv<2,  16, true >( 1, fw, fb, gw, gb, rw, rb, bufA, bufB, h, skip, tid);
    layerv<4,  32, true >( 2, fw, fb, gw, gb, rw, rb, bufB, bufA, h, skip, tid);
    layerv<8,  64, true >( 3, fw, fb, gw, gb, rw, rb, bufA, bufB, h, skip, tid);
    layerv<6,  88, true >( 4, fw, fb, gw, gb, rw, rb, bufB, bufA, h, skip, tid);
    layerv<2,  96, true >( 5, fw, fb, gw, gb, rw, rb, bufA, bufB, h, skip, tid);
    layerv<4, 112, true >( 6, fw, fb, gw, gb, rw, rb, bufB, bufA, h, skip, tid);
    layerv<8, 144, true >( 7, fw, fb, gw, gb, rw, rb, bufA, bufB, h, skip, tid);
    layerv<6, 168, true >( 8, fw, fb, gw, gb, rw, rb, bufB, bufA, h, skip, tid);
    layerv<2, 176, true >( 9, fw, fb, gw, gb, rw, rb, bufA, bufB, h, skip, tid);
    layerv<4, 192, true >(10, fw, fb, gw, gb, rw, rb, bufB, bufA, h, skip, tid);
    layerv<8, 224, true >(11, fw, fb, gw, gb, rw, rb, bufA, bufB, h, skip, tid);
    layerv<6, 248, true >(12, fw, fb, gw, gb, rw, rb, bufB, bufA, h, skip, tid);
    layerv<2, 256, true >(13, fw, fb, gw, gb, rw, rb, bufA, bufB, h, skip, tid);
    layerv<4, 272, true >(14, fw, fb, gw, gb, rw, rb, bufB, bufA, h, skip, tid);
    layerv<8, 304, true >(15, fw, fb, gw, gb, rw, rb, bufA, bufB, h, skip, tid);
    layerv<6, 328, true >(16, fw, fb, gw, gb, rw, rb, bufB, bufA, h, skip, tid);
    layerv<2, 336, true >(17, fw, fb, gw, gb, rw, rb, bufA, bufB, h, skip, tid);
    layerv<4, 352, true >(18, fw, fb, gw, gb, rw, rb, bufB, bufA, h, skip, tid);
    layerv<8, 384, true >(19, fw, fb, gw, gb, rw, rb, bufA, bufB, h, skip, tid);
    layerv<6, 408, true >(20, fw, fb, gw, gb, rw, rb, bufB, bufA, h, skip, tid);
    layerv<2, 416, true >(21, fw, fb, gw, gb, rw, rb, bufA, bufB, h, skip, tid);
    layerv<4, 432, true >(22, fw, fb, gw, gb, rw, rb, bufB, bufA, h, skip, tid);
    layerv<8, 464, true >(23, fw, fb, gw, gb, rw, rb, bufA, bufB, h, skip, tid);
    layerv<6, 488, true >(24, fw, fb, gw, gb, rw, rb, bufB, bufA, h, skip, tid);
    layerv<2, 496, true >(25, fw, fb, gw, gb, rw, rb, bufA, bufB, h, skip, tid);
    layerv<4, 512, true >(26, fw, fb, gw, gb, rw, rb, bufB, bufA, h, skip, tid);
    layerv<8, 544, true >(27, fw, fb, gw, gb, rw, rb, bufA, bufB, h, skip, tid);
    layerv<6, 568, true >(28, fw, fb, gw, gb, rw, rb, bufB, bufA, h, skip, tid);
    layerv<2, 576, false>(29, fw, fb, gw, gb, rw, rb, bufA, bufB, h, skip, tid);

    // epilogue: 1x1 convs + mu-law expand; write e = exp(v); partial sum
    const float w1 = c1w[0], b1 = c1b[0], w2 = c2w[0], b2 = c2b[0];
    float s = 0.0f;
    float* er = eout + (size_t)row * T_LEN;
    #pragma unroll
    for (int p = 0; p < PPT; ++p) {
        const int i2 = 2 * (tid + p * NT);
        if (i2 >= HALO) {
            const int t = t0 + i2 - HALO;
            if (t < T_LEN) {
                f32x2 sk = skip[p];
                float ox = fmaf(fmaxf(sk.x, 0.0f), w1, b1);
                float oy = fmaf(fmaxf(sk.y, 0.0f), w1, b1);
                ox = fmaf(fmaxf(ox, 0.0f), w2, b2);
                oy = fmaf(fmaxf(oy, 0.0f), w2, b2);
                float vx = fmaf(EXP2(8.0f * fabsf(ox)), (1.0f/255.0f), -(1.0f/255.0f));
                float vy = fmaf(EXP2(8.0f * fabsf(oy)), (1.0f/255.0f), -(1.0f/255.0f));
                vx = copysignf(vx, ox);
                vy = copysignf(vy, oy);
                const float ex = __expf(vx);
                const float ey = __expf(vy);
                f32x2 e; e.x = ex; e.y = ey;
                *(f32x2*)&er[t] = e;
                s += ex + ey;
            }
        }
    }
    #pragma unroll
    for (int off = 32; off >= 1; off >>= 1) s += __shfl_xor(s, off, 64);
    if ((tid & 63) == 0) reds[tid >> 6] = s;
    __syncthreads();
    if (tid == 0) {
        float ss = 0.0f;
        #pragma unroll
        for (int w = 0; w < NT / 64; ++w) ss += reds[w];
        partsum[blockIdx.x] = ss;
    }
}

// ---------------------------------------------------------------------------
__global__ __launch_bounds__(256)
void k_scale(float* __restrict__ ebuf, const float* __restrict__ partsum)
{
    const int tid = threadIdx.x;
    const int row = blockIdx.x / RB;

    __shared__ float red[4];
    float s = 0.0f;
    for (int j = tid; j < PB; j += 256) s += partsum[row * PB + j];
    #pragma unroll
    for (int off = 32; off >= 1; off >>= 1) s += __shfl_xor(s, off, 64);
    if ((tid & 63) == 0) red[tid >> 6] = s;
    __syncthreads();
    const float tot = (red[0] + red[1]) + (red[2] + red[3]);
    const float inv = 1.0f / tot;

    float4* vp = (float4*)(ebuf + (size_t)blockIdx.x * CH);
    #pragma unroll
    for (int q = 0; q < 4; ++q) {
        float4 v = vp[tid + q * 256];
        v.x *= inv; v.y *= inv; v.z *= inv; v.w *= inv;
        vp[tid + q * 256] = v;
    }
}

// ---------------------------------------------------------------------------
extern "C" void kernel_launch(void* const* d_in, const int* in_sizes, int n_in,
                              void* d_out, int out_size, void* d_ws, size_t ws_size,
                              hipStream_t stream)
{
    const float* x   = (const float*)d_in[0];
    const float* cw  = (const float*)d_in[1];
    const float* cb  = (const float*)d_in[2];
    const float* fw  = (const float*)d_in[3];
    const float* fb  = (const float*)d_in[4];
    const float* gw  = (const float*)d_in[5];
    const float* gb  = (const float*)d_in[6];
    const float* rw  = (const float*)d_in[7];
    const float* rb  = (const float*)d_in[8];
    const float* c1w = (const float*)d_in[9];
    const float* c1b = (const float*)d_in[10];
    const float* c2w = (const float*)d_in[11];
    const float* c2b = (const float*)d_in[12];

    float* eout    = (float*)d_out;
    float* partsum = (float*)d_ws;            // NROW*PB = 848 floats

    k_wavenet<<<NROW * PB, NT, 0, stream>>>(x, cw, cb, fw, fb, gw, gb, rw, rb,
                                            c1w, c1b, c2w, c2b, eout, partsum);
    k_scale<<<NB2, 256, 0, stream>>>(eout, partsum);
}